// Round 3
// baseline (86.915 us; speedup 1.0000x reference)
//
#include <hip/hip_runtime.h>

#define BB 8
#define NN 4096
#define BLK 512
#define RPT 8
#define ROWS 128                  // source rows per block
#define SLICES 32                 // j-slices, one per 16-lane group (tid>>4)
#define JSL (NN/SLICES)           // 128 targets per slice
#define NPAIR (JSL/2)             // 64 j-pairs per slice
#define PADP (NPAIR + 1)          // pad slice stride to 65 float4: slice bank offset = 4*s mod 32
#define NWAVE (BLK/64)            // 8 waves per block
#define MAGIC 0x3A9C6E17u         // flag hi32 marker; ws poison fill resets flags each iter

typedef float f32x2 __attribute__((ext_vector_type(2)));

// Packed fp32 FMA: two independent fp32 fmas per lane-slot (VOP3P, gfx90a+).
// Bit-identical per-component to scalar fmaf.
__device__ __forceinline__ f32x2 pk_fma(f32x2 a, f32x2 b, f32x2 c) {
    f32x2 d;
    asm("v_pk_fma_f32 %0, %1, %2, %3" : "=v"(d) : "v"(a), "v"(b), "v"(c));
    return d;
}

// Single fused kernel. Each block owns ROWS source rows for one (dir, batch),
// scans ALL NN targets staged in LDS in pair-SoA form so the inner loop runs
// on v_pk_fma_f32 (2 target-points per packed op): per j-pair per row,
// 3 pk_fma + 1 min3 = 2.0 lane-slots/pair vs 3.5 scalar. Block (0,0,0)
// gathers the 512 partials via MAGIC-tagged flags (no second dispatch).
__global__ __launch_bounds__(BLK, 4) void cd_main(const float* __restrict__ src,
                                                  const float* __restrict__ tgt,
                                                  unsigned long long* __restrict__ flag,
                                                  float* __restrict__ out) {
    __shared__ float4 tlA[SLICES * PADP];    // 32.5 KB: {x0,x1,y0,y1} per j-pair
    __shared__ float4 tlB[SLICES * PADP];    // 32.5 KB: {z0,z1,w0,w1}, w = 0.5|t|^2
    __shared__ float pmin[NWAVE * ROWS];     // 4 KB per-wave row mins
    __shared__ float bsum[NWAVE];
    const int dir = blockIdx.z;
    const float* Sp = dir ? tgt : src;
    const float* Tp = dir ? src : tgt;
    const int b   = blockIdx.y;
    const int rt  = blockIdx.x;
    const int tid = threadIdx.x;

    // Stage all targets in pair-SoA form. Contiguous b128 writes (max-throughput
    // pattern); 24 scalar global loads/thread, L2-hot (inputs total 786 KB).
    const float* tb = Tp + (size_t)b * NN * 3;
    for (int P = tid; P < NN/2; P += BLK) {
        const float* t6 = tb + 6*P;
        float x0 = t6[0], y0 = t6[1], z0 = t6[2];
        float x1 = t6[3], y1 = t6[4], z1 = t6[5];
        int s = P >> 6, p = P & (NPAIR - 1);
        tlA[s*PADP + p] = make_float4(x0, x1, y0, y1);
        tlB[s*PADP + p] = make_float4(z0, z1,
                                      0.5f*(x0*x0 + y0*y0 + z0*z0),
                                      0.5f*(x1*x1 + y1*y1 + z1*z1));
    }

    // Per-thread source rows (16-lane strided, L2-hot). Coefficients kept as
    // broadcast pairs to feed pk_fma directly.
    const float* sb = Sp + (size_t)b * NN * 3;
    const int sub   = tid & 15;
    const int slice = tid >> 4;              // 0..31; 4 slices per wave
    const int rowBase = rt * ROWS;
    f32x2 nx2[RPT], ny2[RPT], nz2[RPT];
    float q[RPT];
#pragma unroll
    for (int r = 0; r < RPT; ++r) {
        int row = rowBase + sub + 16*r;
        float x = sb[3*row], y = sb[3*row+1], z = sb[3*row+2];
        nx2[r].x = -x; nx2[r].y = -x;
        ny2[r].x = -y; ny2[r].y = -y;
        nz2[r].x = -z; nz2[r].y = -z;
        q[r] = 0.5f*(x*x + y*y + z*z);
    }
    __syncthreads();

    // min over this slice's j of (0.5|t|^2 - <s,t>); row-constant 0.5|s|^2
    // added after the min. Packed: each j-pair costs 3 pk_fma + 1 min3 per row.
    // fma chain order matches the scalar version -> bit-identical results.
    float m[RPT];
#pragma unroll
    for (int r = 0; r < RPT; ++r) m[r] = 1.0e30f;

    const float4* Ap = tlA + slice * PADP;   // wave: 4 broadcast addrs, disjoint banks
    const float4* Bp = tlB + slice * PADP;
#pragma unroll 2
    for (int p = 0; p < NPAIR; ++p) {
        float4 a = Ap[p];
        float4 c = Bp[p];
        f32x2 TX, TY, TZ, TW;
        TX.x = a.x; TX.y = a.y;
        TY.x = a.z; TY.y = a.w;
        TZ.x = c.x; TZ.y = c.y;
        TW.x = c.z; TW.y = c.w;
#pragma unroll
        for (int r = 0; r < RPT; ++r) {
            f32x2 t = pk_fma(nx2[r], TX, pk_fma(ny2[r], TY, pk_fma(nz2[r], TZ, TW)));
            m[r] = fminf(m[r], fminf(t.x, t.y));
        }
    }

    // Combine the wave's 4 slice-groups in-register (lanes xor 16, 32),
    // then lanes 0..15 of each wave publish per-row partials.
#pragma unroll
    for (int r = 0; r < RPT; ++r) {
        float v = m[r];
        v = fminf(v, __shfl_xor(v, 16, 64));
        v = fminf(v, __shfl_xor(v, 32, 64));
        m[r] = v + q[r];
    }
    const int wid = tid >> 6;
    if ((tid & 63) < 16) {
#pragma unroll
        for (int r = 0; r < RPT; ++r)
            pmin[wid*ROWS + sub + 16*r] = m[r];
    }
    __syncthreads();

    // Threads 0..127: combine 8 wave-partials per row, then sqrt(2*d2half).
    float dsum = 0.0f;
    if (tid < ROWS) {
        float v = pmin[tid];
#pragma unroll
        for (int s = 1; s < NWAVE; ++s) v = fminf(v, pmin[s*ROWS + tid]);
        v = fmaxf(v, 0.0f);
        dsum = sqrtf(2.0f * v);
    }
    // Block sum (inactive threads contribute 0).
#pragma unroll
    for (int o = 32; o > 0; o >>= 1) dsum += __shfl_down(dsum, o, 64);
    if ((tid & 63) == 0) bsum[tid >> 6] = dsum;
    __syncthreads();
    if (tid == 0) {
        float t = 0.0f;
#pragma unroll
        for (int w = 0; w < NWAVE; ++w) t += bsum[w];
        const int idx = ((dir * BB + b) * 32) + rt;
        unsigned long long pk = ((unsigned long long)MAGIC << 32)
                              | (unsigned long long)__float_as_uint(t);
        __hip_atomic_store(&flag[idx], pk, __ATOMIC_RELAXED, __HIP_MEMORY_SCOPE_AGENT);
    }

    // Block (0,0,0): gather all 512 partials and finalize.
    if ((rt | b | dir) == 0) {
        __syncthreads();                     // bsum reuse; tid0's flag store done
        unsigned long long v;
        do {
            __builtin_amdgcn_s_sleep(1);
            v = __hip_atomic_load(&flag[tid], __ATOMIC_RELAXED, __HIP_MEMORY_SCOPE_AGENT);
        } while ((unsigned)(v >> 32) != MAGIC);
        float val = __uint_as_float((unsigned)(v & 0xFFFFFFFFull));
#pragma unroll
        for (int o = 32; o > 0; o >>= 1) val += __shfl_down(val, o, 64);
        if ((tid & 63) == 0) bsum[tid >> 6] = val;
        __syncthreads();
        if (tid == 0) {
            float t = 0.0f;
#pragma unroll
            for (int w = 0; w < NWAVE; ++w) t += bsum[w];
            out[0] = t * (1.0f / (float)(BB * NN));   // mean(term1) + mean(term2)
        }
    }
}

extern "C" void kernel_launch(void* const* d_in, const int* in_sizes, int n_in,
                              void* d_out, int out_size, void* d_ws, size_t ws_size,
                              hipStream_t stream) {
    const float* src = (const float*)d_in[0];
    const float* tgt = (const float*)d_in[1];
    unsigned long long* flag = (unsigned long long*)d_ws;  // 512 u64; poison fill != MAGIC
    float* out = (float*)d_out;

    dim3 grid(NN/ROWS, BB, 2);         // 32 x 8 x 2 = 512 blocks, one dispatch total
    cd_main<<<grid, BLK, 0, stream>>>(src, tgt, flag, out);
}

// Round 4
// 76.778 us; speedup vs baseline: 1.1320x; 1.1320x over previous
//
#include <hip/hip_runtime.h>

#define BB 8
#define NN 4096
#define BLK 512
#define RPT 8
#define ROWS 128                  // source rows per block
#define SLICES 32                 // j-slices, one per 16-lane group (tid>>4)
#define JSL (NN/SLICES)           // 128 targets per slice
#define PADJ (JSL + 1)            // +16B pad/slice: slice base bank offset = 4*slice mod 32
#define NWAVE (BLK/64)            // 8 waves per block
#define MAGIC 0x3A9C6E17u         // flag hi32 marker; ws poison fill resets flags each iter

// Single 3-operand min. LLVM won't fuse fminf(fminf) into v_min3_f32 without
// fast-math (IEEE minnum conservatism); for our finite values it's exact.
// NOTE: keep inline asm to ONE inst with scalar operands — the R3 experiment
// showed multi-op asm chains (v_pk_fma_f32) force operand repacking and
// defeat the scheduler (40.9 us vs 18.5 us). pk_fma is also half-rate on
// gfx950 (157.3 TF spec = scalar v_fma rate), so packed fp32 gains nothing.
__device__ __forceinline__ float min3f(float a, float b, float c) {
    float d;
    asm("v_min3_f32 %0, %1, %2, %3" : "=v"(d) : "v"(a), "v"(b), "v"(c));
    return d;
}

// Single fused kernel. Each block owns ROWS source rows for one (dir, batch),
// scans ALL NN targets (staged once in LDS), publishes its partial sum as
// (MAGIC<<32 | float_bits) via agent-scope atomic store; block (0,0,0) polls
// all 512 flags and finalizes. Inner loop: 3 fma + 0.5 min3 = 3.5 lane-slots
// per pair; 268.4M pairs -> ~940M slots ≈ 16.5 us at sustained VALU rate.
__global__ __launch_bounds__(BLK, 4) void cd_main(const float* __restrict__ src,
                                                  const float* __restrict__ tgt,
                                                  unsigned long long* __restrict__ flag,
                                                  float* __restrict__ out) {
    __shared__ float4 tl[SLICES * PADJ];     // 64.5 KB: (x, y, z, 0.5*|t|^2), padded
    __shared__ float pmin[NWAVE * ROWS];     // 4 KB per-wave row mins
    __shared__ float bsum[NWAVE];
    const int dir = blockIdx.z;
    const float* Sp = dir ? tgt : src;
    const float* Tp = dir ? src : tgt;
    const int b   = blockIdx.y;
    const int rt  = blockIdx.x;
    const int tid = threadIdx.x;

    // Stage all targets: (x,y,z, 0.5|t|^2). float4 loads: 4 points per 3 loads
    // (48B groups, 16B-aligned). L2-hot (inputs total 786 KB).
    const float* tb = Tp + (size_t)b * NN * 3;
    for (int g = tid; g < NN/4; g += BLK) {
        const float4* t4 = (const float4*)(tb + 12*g);
        float4 v0 = t4[0], v1 = t4[1], v2 = t4[2];
        float px[4] = {v0.x, v0.w, v1.z, v2.y};
        float py[4] = {v0.y, v1.x, v1.w, v2.z};
        float pz[4] = {v0.z, v1.y, v2.x, v2.w};
        int k0 = 4*g;
        int base = (k0 >> 7) * PADJ + (k0 & (JSL - 1));   // 4 points share a slice
#pragma unroll
        for (int i = 0; i < 4; ++i)
            tl[base + i] = make_float4(px[i], py[i], pz[i],
                                       0.5f*(px[i]*px[i] + py[i]*py[i] + pz[i]*pz[i]));
    }

    // Per-thread source rows (16-lane strided, L2-hot).
    const float* sb = Sp + (size_t)b * NN * 3;
    const int sub   = tid & 15;
    const int slice = tid >> 4;              // 0..31; 4 slices per wave
    const int rowBase = rt * ROWS;
    float nx[RPT], ny[RPT], nz[RPT], q[RPT];
#pragma unroll
    for (int r = 0; r < RPT; ++r) {
        int row = rowBase + sub + 16*r;
        float x = sb[3*row], y = sb[3*row+1], z = sb[3*row+2];
        nx[r] = -x; ny[r] = -y; nz[r] = -z;
        q[r] = 0.5f*(x*x + y*y + z*z);
    }
    __syncthreads();

    // min over this slice's j of (0.5|t|^2 - <s,t>); row-constant 0.5|s|^2
    // added after the min. One v_min3 per j-pair per row.
    float m[RPT];
#pragma unroll
    for (int r = 0; r < RPT; ++r) m[r] = 1.0e30f;

    const float4* tp = tl + slice * PADJ;
#pragma unroll 2
    for (int j = 0; j < JSL; j += 2) {
        float4 t0 = tp[j];        // 4 distinct padded addrs/wave -> conflict-free
        float4 t1 = tp[j+1];
#pragma unroll
        for (int r = 0; r < RPT; ++r) {
            float a0 = fmaf(nx[r], t0.x, fmaf(ny[r], t0.y, fmaf(nz[r], t0.z, t0.w)));
            float a1 = fmaf(nx[r], t1.x, fmaf(ny[r], t1.y, fmaf(nz[r], t1.z, t1.w)));
            m[r] = min3f(m[r], a0, a1);
        }
    }

    // Combine the wave's 4 slice-groups in-register (lanes xor 16, 32),
    // then lanes 0..15 of each wave publish per-row partials.
#pragma unroll
    for (int r = 0; r < RPT; ++r) {
        float v = m[r];
        v = fminf(v, __shfl_xor(v, 16, 64));
        v = fminf(v, __shfl_xor(v, 32, 64));
        m[r] = v + q[r];
    }
    const int wid = tid >> 6;
    if ((tid & 63) < 16) {
#pragma unroll
        for (int r = 0; r < RPT; ++r)
            pmin[wid*ROWS + sub + 16*r] = m[r];
    }
    __syncthreads();

    // Threads 0..127: combine 8 wave-partials per row, then sqrt(2*d2half).
    float dsum = 0.0f;
    if (tid < ROWS) {
        float v = pmin[tid];
#pragma unroll
        for (int s = 1; s < NWAVE; ++s) v = fminf(v, pmin[s*ROWS + tid]);
        v = fmaxf(v, 0.0f);
        dsum = sqrtf(2.0f * v);
    }
    // Block sum (inactive threads contribute 0).
#pragma unroll
    for (int o = 32; o > 0; o >>= 1) dsum += __shfl_down(dsum, o, 64);
    if ((tid & 63) == 0) bsum[tid >> 6] = dsum;
    __syncthreads();
    if (tid == 0) {
        float t = 0.0f;
#pragma unroll
        for (int w = 0; w < NWAVE; ++w) t += bsum[w];
        const int idx = ((dir * BB + b) * 32) + rt;
        unsigned long long pk = ((unsigned long long)MAGIC << 32)
                              | (unsigned long long)__float_as_uint(t);
        __hip_atomic_store(&flag[idx], pk, __ATOMIC_RELAXED, __HIP_MEMORY_SCOPE_AGENT);
    }

    // Block (0,0,0): gather all 512 partials and finalize.
    if ((rt | b | dir) == 0) {
        __syncthreads();                     // bsum reuse; tid0's flag store done
        unsigned long long v;
        do {
            __builtin_amdgcn_s_sleep(1);
            v = __hip_atomic_load(&flag[tid], __ATOMIC_RELAXED, __HIP_MEMORY_SCOPE_AGENT);
        } while ((unsigned)(v >> 32) != MAGIC);
        float val = __uint_as_float((unsigned)(v & 0xFFFFFFFFull));
#pragma unroll
        for (int o = 32; o > 0; o >>= 1) val += __shfl_down(val, o, 64);
        if ((tid & 63) == 0) bsum[tid >> 6] = val;
        __syncthreads();
        if (tid == 0) {
            float t = 0.0f;
#pragma unroll
            for (int w = 0; w < NWAVE; ++w) t += bsum[w];
            out[0] = t * (1.0f / (float)(BB * NN));   // mean(term1) + mean(term2)
        }
    }
}

extern "C" void kernel_launch(void* const* d_in, const int* in_sizes, int n_in,
                              void* d_out, int out_size, void* d_ws, size_t ws_size,
                              hipStream_t stream) {
    const float* src = (const float*)d_in[0];
    const float* tgt = (const float*)d_in[1];
    unsigned long long* flag = (unsigned long long*)d_ws;  // 512 u64; poison fill != MAGIC
    float* out = (float*)d_out;

    dim3 grid(NN/ROWS, BB, 2);         // 32 x 8 x 2 = 512 blocks, one dispatch total
    cd_main<<<grid, BLK, 0, stream>>>(src, tgt, flag, out);
}

// Round 5
// 75.894 us; speedup vs baseline: 1.1452x; 1.0117x over previous
//
#include <hip/hip_runtime.h>

#define BB 8
#define NN 4096
#define BLK 512
#define RPT 8
#define ROWS 128                  // source rows per block
#define SLICES 32                 // j-slices, one per 16-lane group (tid>>4)
#define HALF 2048                 // targets staged per half (2 halves)
#define JSLH (HALF/SLICES)        // 64 targets per slice per half
#define PADH (JSLH + 1)           // 65-float4 slice stride: slice base bank = 4*s mod 32
#define NWAVE (BLK/64)            // 8 waves per block
#define MAGIC 0x3A9C6E17u         // flag hi32 marker; ws poison fill resets flags each iter

// Single 3-operand min (exact for finite values). ONE inst, scalar operands —
// multi-op asm chains (R3's v_pk_fma_f32) force repacking and defeat the
// scheduler. pk fp32 is also half-rate on gfx950 (157.3 TF = scalar rate).
__device__ __forceinline__ float min3f(float a, float b, float c) {
    float d;
    asm("v_min3_f32 %0, %1, %2, %3" : "=v"(d) : "v"(a), "v"(b), "v"(c));
    return d;
}

// Single fused kernel. Each block owns ROWS source rows for one (dir, batch)
// and scans ALL NN targets, staged in LDS in TWO 2048-point halves so the
// block's LDS footprint is 37.4 KB -> 4 blocks/CU -> 8 waves/SIMD (was 2
// blocks/CU at 71 KB). Both VALU (~72%) and LDS-return (~61%) pipes were
// partially stalled at 4 waves/SIMD; doubled occupancy covers the ~120-cyc
// ds_read latency. Inner math unchanged: 3 fma + 0.5 min3 = 3.5 slots/pair,
// pipe floor ~12 us. Block (0,0,0) gathers 512 MAGIC-tagged partials (no
// second dispatch).
__global__ __launch_bounds__(BLK, 8) void cd_main(const float* __restrict__ src,
                                                  const float* __restrict__ tgt,
                                                  unsigned long long* __restrict__ flag,
                                                  float* __restrict__ out) {
    __shared__ float4 tl[SLICES * PADH];     // 33.3 KB: (x, y, z, 0.5*|t|^2), padded
    __shared__ float pmin[NWAVE * ROWS];     // 4 KB per-wave row mins
    __shared__ float bsum[NWAVE];
    const int dir = blockIdx.z;
    const float* Sp = dir ? tgt : src;
    const float* Tp = dir ? src : tgt;
    const int b   = blockIdx.y;
    const int rt  = blockIdx.x;
    const int tid = threadIdx.x;

    const float* tb = Tp + (size_t)b * NN * 3;

    // Per-thread source rows (16-lane strided, L2-hot).
    const float* sb = Sp + (size_t)b * NN * 3;
    const int sub   = tid & 15;
    const int slice = tid >> 4;              // 0..31; 4 slices per wave
    const int rowBase = rt * ROWS;
    float nx[RPT], ny[RPT], nz[RPT], q[RPT];
#pragma unroll
    for (int r = 0; r < RPT; ++r) {
        int row = rowBase + sub + 16*r;
        float x = sb[3*row], y = sb[3*row+1], z = sb[3*row+2];
        nx[r] = -x; ny[r] = -y; nz[r] = -z;
        q[r] = 0.5f*(x*x + y*y + z*z);
    }

    // min over all j of (0.5|t|^2 - <s,t>); row-constant 0.5|s|^2 added after.
    float m[RPT];
#pragma unroll
    for (int r = 0; r < RPT; ++r) m[r] = 1.0e30f;

    for (int h = 0; h < 2; ++h) {
        if (h) __syncthreads();              // previous scan done before overwrite
        // Stage this half: lane-contiguous float4 writes -> even bank spread
        // (R4's 4-consecutive-per-thread pattern was a 4x write serialize).
#pragma unroll
        for (int i = 0; i < HALF/BLK; ++i) {
            int k = tid + i*BLK;
            const float* p = tb + (size_t)h*(HALF*3) + 3*k;
            float x = p[0], y = p[1], z = p[2];
            tl[(k >> 6) * PADH + (k & (JSLH - 1))] =
                make_float4(x, y, z, 0.5f*(x*x + y*y + z*z));
        }
        __syncthreads();

        const float4* tp = tl + slice * PADH;
#pragma unroll 2
        for (int j = 0; j < JSLH; j += 2) {
            float4 t0 = tp[j];    // 4 distinct padded addrs/wave -> conflict-free
            float4 t1 = tp[j+1];
#pragma unroll
            for (int r = 0; r < RPT; ++r) {
                float a0 = fmaf(nx[r], t0.x, fmaf(ny[r], t0.y, fmaf(nz[r], t0.z, t0.w)));
                float a1 = fmaf(nx[r], t1.x, fmaf(ny[r], t1.y, fmaf(nz[r], t1.z, t1.w)));
                m[r] = min3f(m[r], a0, a1);
            }
        }
    }

    // Combine the wave's 4 slice-groups in-register (lanes xor 16, 32),
    // then lanes 0..15 of each wave publish per-row partials.
#pragma unroll
    for (int r = 0; r < RPT; ++r) {
        float v = m[r];
        v = fminf(v, __shfl_xor(v, 16, 64));
        v = fminf(v, __shfl_xor(v, 32, 64));
        m[r] = v + q[r];
    }
    const int wid = tid >> 6;
    __syncthreads();                         // scan reads done before pmin reuse
    if ((tid & 63) < 16) {
#pragma unroll
        for (int r = 0; r < RPT; ++r)
            pmin[wid*ROWS + sub + 16*r] = m[r];
    }
    __syncthreads();

    // Threads 0..127: combine 8 wave-partials per row, then sqrt(2*d2half).
    float dsum = 0.0f;
    if (tid < ROWS) {
        float v = pmin[tid];
#pragma unroll
        for (int s = 1; s < NWAVE; ++s) v = fminf(v, pmin[s*ROWS + tid]);
        v = fmaxf(v, 0.0f);
        dsum = sqrtf(2.0f * v);
    }
    // Block sum (inactive threads contribute 0).
#pragma unroll
    for (int o = 32; o > 0; o >>= 1) dsum += __shfl_down(dsum, o, 64);
    if ((tid & 63) == 0) bsum[tid >> 6] = dsum;
    __syncthreads();
    if (tid == 0) {
        float t = 0.0f;
#pragma unroll
        for (int w = 0; w < NWAVE; ++w) t += bsum[w];
        const int idx = ((dir * BB + b) * 32) + rt;
        unsigned long long pk = ((unsigned long long)MAGIC << 32)
                              | (unsigned long long)__float_as_uint(t);
        __hip_atomic_store(&flag[idx], pk, __ATOMIC_RELAXED, __HIP_MEMORY_SCOPE_AGENT);
    }

    // Block (0,0,0): gather all 512 partials and finalize.
    if ((rt | b | dir) == 0) {
        __syncthreads();                     // bsum reuse; tid0's flag store done
        unsigned long long v;
        do {
            __builtin_amdgcn_s_sleep(1);
            v = __hip_atomic_load(&flag[tid], __ATOMIC_RELAXED, __HIP_MEMORY_SCOPE_AGENT);
        } while ((unsigned)(v >> 32) != MAGIC);
        float val = __uint_as_float((unsigned)(v & 0xFFFFFFFFull));
#pragma unroll
        for (int o = 32; o > 0; o >>= 1) val += __shfl_down(val, o, 64);
        if ((tid & 63) == 0) bsum[tid >> 6] = val;
        __syncthreads();
        if (tid == 0) {
            float t = 0.0f;
#pragma unroll
            for (int w = 0; w < NWAVE; ++w) t += bsum[w];
            out[0] = t * (1.0f / (float)(BB * NN));   // mean(term1) + mean(term2)
        }
    }
}

extern "C" void kernel_launch(void* const* d_in, const int* in_sizes, int n_in,
                              void* d_out, int out_size, void* d_ws, size_t ws_size,
                              hipStream_t stream) {
    const float* src = (const float*)d_in[0];
    const float* tgt = (const float*)d_in[1];
    unsigned long long* flag = (unsigned long long*)d_ws;  // 512 u64; poison fill != MAGIC
    float* out = (float*)d_out;

    dim3 grid(NN/ROWS, BB, 2);         // 32 x 8 x 2 = 512 blocks, one dispatch total
    cd_main<<<grid, BLK, 0, stream>>>(src, tgt, flag, out);
}

// Round 7
// 75.143 us; speedup vs baseline: 1.1567x; 1.0100x over previous
//
#include <hip/hip_runtime.h>

#define BB 8
#define NN 4096
#define BLK 1024
#define RPT 8
#define ROWS 128                  // source rows per block
#define SLICES 64                 // j-slices, one per 16-lane group (tid>>4)
#define HALF 2048                 // targets staged per half (2 halves)
#define JSLH (HALF/SLICES)        // 32 targets per slice per half
#define PADH (JSLH + 1)           // 33-float4 slice stride (528 B): slice base bank = 4*s mod 32
#define NWAVE (BLK/64)            // 16 waves per block
#define MAGIC 0x3A9C6E17u         // flag hi32 marker; ws poison fill resets flags each iter

// Single 3-operand min (exact for finite values). ONE inst, scalar operands —
// multi-op asm chains (R3's v_pk_fma_f32) force repacking and defeat the
// scheduler. pk fp32 is also half-rate on gfx950 (157.3 TF = scalar rate).
__device__ __forceinline__ float min3f(float a, float b, float c) {
    float d;
    asm("v_min3_f32 %0, %1, %2, %3" : "=v"(d) : "v"(a), "v"(b), "v"(c));
    return d;
}

// Single fused kernel, BLK=1024 occupancy experiment: same aggregate VALU
// slots, same aggregate ds_read_b128 count, same bank geometry as the
// BLK=512 version — but 2 resident blocks/CU x 16 waves = 8 waves/SIMD
// (was 4), to cover the ~120-cyc ds_read latency. Each block owns ROWS
// source rows for one (dir, batch), scans ALL NN targets staged in two
// 2048-point LDS halves. Inner: 3 fma + 0.5 min3 = 3.5 slots/pair.
// Block (0,0,0) gathers 512 MAGIC-tagged partials (no second dispatch).
__global__ __launch_bounds__(BLK, 8) void cd_main(const float* __restrict__ src,
                                                  const float* __restrict__ tgt,
                                                  unsigned long long* __restrict__ flag,
                                                  float* __restrict__ out) {
    __shared__ float4 tl[SLICES * PADH];     // 33.8 KB: (x, y, z, 0.5*|t|^2), padded
    __shared__ float pmin[NWAVE * ROWS];     // 8 KB per-wave row mins
    __shared__ float bsum[NWAVE];
    const int dir = blockIdx.z;
    const float* Sp = dir ? tgt : src;
    const float* Tp = dir ? src : tgt;
    const int b   = blockIdx.y;
    const int rt  = blockIdx.x;
    const int tid = threadIdx.x;

    const float* tb = Tp + (size_t)b * NN * 3;

    // Per-thread source rows (16-lane strided, L2-hot).
    const float* sb = Sp + (size_t)b * NN * 3;
    const int sub   = tid & 15;
    const int slice = tid >> 4;              // 0..63; 4 slices per wave
    const int rowBase = rt * ROWS;
    float nx[RPT], ny[RPT], nz[RPT], q[RPT];
#pragma unroll
    for (int r = 0; r < RPT; ++r) {
        int row = rowBase + sub + 16*r;
        float x = sb[3*row], y = sb[3*row+1], z = sb[3*row+2];
        nx[r] = -x; ny[r] = -y; nz[r] = -z;
        q[r] = 0.5f*(x*x + y*y + z*z);
    }

    // min over all j of (0.5|t|^2 - <s,t>); row-constant 0.5|s|^2 added after.
    float m[RPT];
#pragma unroll
    for (int r = 0; r < RPT; ++r) m[r] = 1.0e30f;

    for (int h = 0; h < 2; ++h) {
        if (h) __syncthreads();              // previous scan done before overwrite
        // Stage this half: lane-contiguous float4 writes -> even bank spread.
#pragma unroll
        for (int i = 0; i < HALF/BLK; ++i) {
            int k = tid + i*BLK;
            const float* p = tb + (size_t)h*(HALF*3) + 3*k;
            float x = p[0], y = p[1], z = p[2];
            tl[(k >> 5) * PADH + (k & (JSLH - 1))] =
                make_float4(x, y, z, 0.5f*(x*x + y*y + z*z));
        }
        __syncthreads();

        const float4* tp = tl + slice * PADH;
#pragma unroll 2
        for (int j = 0; j < JSLH; j += 2) {
            float4 t0 = tp[j];    // 4 distinct padded addrs/wave -> conflict-free
            float4 t1 = tp[j+1];
#pragma unroll
            for (int r = 0; r < RPT; ++r) {
                float a0 = fmaf(nx[r], t0.x, fmaf(ny[r], t0.y, fmaf(nz[r], t0.z, t0.w)));
                float a1 = fmaf(nx[r], t1.x, fmaf(ny[r], t1.y, fmaf(nz[r], t1.z, t1.w)));
                m[r] = min3f(m[r], a0, a1);
            }
        }
    }

    // Combine the wave's 4 slice-groups in-register (lanes xor 16, 32),
    // then lanes 0..15 of each wave publish per-row partials.
#pragma unroll
    for (int r = 0; r < RPT; ++r) {
        float v = m[r];
        v = fminf(v, __shfl_xor(v, 16, 64));
        v = fminf(v, __shfl_xor(v, 32, 64));
        m[r] = v + q[r];
    }
    const int wid = tid >> 6;
    __syncthreads();                         // scan reads done before pmin reuse
    if ((tid & 63) < 16) {
#pragma unroll
        for (int r = 0; r < RPT; ++r)
            pmin[wid*ROWS + sub + 16*r] = m[r];
    }
    __syncthreads();

    // Threads 0..127: combine 16 wave-partials per row, then sqrt(2*d2half).
    float dsum = 0.0f;
    if (tid < ROWS) {
        float v = pmin[tid];
#pragma unroll
        for (int s = 1; s < NWAVE; ++s) v = fminf(v, pmin[s*ROWS + tid]);
        v = fmaxf(v, 0.0f);
        dsum = sqrtf(2.0f * v);
    }
    // Block sum (inactive threads contribute exact +0.0f).
#pragma unroll
    for (int o = 32; o > 0; o >>= 1) dsum += __shfl_down(dsum, o, 64);
    if ((tid & 63) == 0) bsum[tid >> 6] = dsum;
    __syncthreads();
    if (tid == 0) {
        float t = 0.0f;
#pragma unroll
        for (int w = 0; w < NWAVE; ++w) t += bsum[w];
        const int idx = ((dir * BB + b) * 32) + rt;
        unsigned long long pk = ((unsigned long long)MAGIC << 32)
                              | (unsigned long long)__float_as_uint(t);
        __hip_atomic_store(&flag[idx], pk, __ATOMIC_RELAXED, __HIP_MEMORY_SCOPE_AGENT);
    }

    // Block (0,0,0): gather all 512 partials and finalize.
    if ((rt | b | dir) == 0) {
        __syncthreads();                     // bsum reuse; tid0's flag store done
        float val = 0.0f;
        if (tid < 512) {
            unsigned long long v;
            do {
                __builtin_amdgcn_s_sleep(1);
                v = __hip_atomic_load(&flag[tid], __ATOMIC_RELAXED, __HIP_MEMORY_SCOPE_AGENT);
            } while ((unsigned)(v >> 32) != MAGIC);
            val = __uint_as_float((unsigned)(v & 0xFFFFFFFFull));
        }
#pragma unroll
        for (int o = 32; o > 0; o >>= 1) val += __shfl_down(val, o, 64);
        if ((tid & 63) == 0) bsum[tid >> 6] = val;
        __syncthreads();
        if (tid == 0) {
            float t = 0.0f;
#pragma unroll
            for (int w = 0; w < NWAVE; ++w) t += bsum[w];
            out[0] = t * (1.0f / (float)(BB * NN));   // mean(term1) + mean(term2)
        }
    }
}

extern "C" void kernel_launch(void* const* d_in, const int* in_sizes, int n_in,
                              void* d_out, int out_size, void* d_ws, size_t ws_size,
                              hipStream_t stream) {
    const float* src = (const float*)d_in[0];
    const float* tgt = (const float*)d_in[1];
    unsigned long long* flag = (unsigned long long*)d_ws;  // 512 u64; poison fill != MAGIC
    float* out = (float*)d_out;

    dim3 grid(NN/ROWS, BB, 2);         // 32 x 8 x 2 = 512 blocks, one dispatch total
    cd_main<<<grid, BLK, 0, stream>>>(src, tgt, flag, out);
}